// Round 1
// baseline (374.121 us; speedup 1.0000x reference)
//
#include <hip/hip_runtime.h>

typedef float  f32x4 __attribute__((ext_vector_type(4)));
typedef short  s16x8 __attribute__((ext_vector_type(8)));
typedef short  s16x4 __attribute__((ext_vector_type(4)));

#define DEVI static __device__ __forceinline__

DEVI short f2b(float f) {
  unsigned u = __builtin_bit_cast(unsigned, f);
  unsigned r = (u + 0x7FFFu + ((u >> 16) & 1u)) >> 16;   // RNE fp32->bf16
  return (short)(unsigned short)r;
}
DEVI float b2f(short s) {
  unsigned u = ((unsigned)(unsigned short)s) << 16;
  return __builtin_bit_cast(float, u);
}

// sine positional encoding, matches _sine_pos_encoding((8,8), 72) tiled x2 over n
DEVI float pos_val(int n, int c) {
  int i = (n & 63) >> 3, j = n & 7;
  float base; int cc;
  if (c < 72) { base = (float)(i + 1); cc = c; }
  else        { base = (float)(j + 1); cc = c - 72; }
  int m = cc >> 1;
  const float SC  = (float)(6.283185307179586 / 8.000001);   // 2*pi/(8+1e-6)
  const float LNT = (float)(9.210340371976184 / 36.0);       // ln(10000)/36
  float arg = base * SC * __expf(-(float)m * LNT);
  return (cc & 1) ? cosf(arg) : sinf(arg);
}

// LDS geometry:
//  XS : [128][168] bf16  x (later x+pos); cols 144..167 zero (K-pad to 160)
//  QB : [128][40]  bf16  q of head (d pad to 32 w/ zeros); later out_h
//  KB : [128][40]  bf16  k of head
//  VTb: [32][136]  bf16  v^T of head (rows 24..31 zero)
//  AL : 8x[16][136] bf16 per-wave alpha scratch (wave-local, no barrier)
//  WB : [96][168] bf16 qkv-weight strip  OR  [144][40] proj-weight strip
//  RPB: [675][6]  f32   rel-pos-bias table
template<int PATH>
DEVI void run_path(short* XS, short* QB, short* KB, short* VTb, short* AL, short* WB,
                   const float* RPB, const float* __restrict__ Wqkv,
                   const float* __restrict__ w_proj,
                   f32x4 (&oacc)[9], int tid, int w, int lg, int ll)
{
  constexpr int NT   = PATH ? 4 : 8;     // beta col-tiles per wave
  constexpr int NKS  = PATH ? 2 : 4;     // PV K steps
  constexpr int COFF = PATH ? 0 : 144;   // w_proj column offset (mut|self concat)
  constexpr int QXOR = PATH ? 4 : 0;     // mut: out rows n use q rows n^64
  const float SCALE = 0.20412414523193154f;  // 24^-0.5
  const int half  = w >> 2;
  const int mbase = PATH ? half * 64 : 0;
  const int rg = w >> 1, cg = w & 1;
  const f32x4 z4 = {0.f, 0.f, 0.f, 0.f};

  for (int h = 0; h < 6; ++h) {
    __syncthreads();                                   // (a) prev proj reads done
    // ---- stage qkv weight strip head h: WB[96][168], zero-padded (d>=24, kk>=144)
    for (int ch = tid; ch < 96 * 21; ch += 512) {
      int c = ch / 21, k0 = (ch - c * 21) << 3;
      int d = c & 31;
      s16x8 o = {0,0,0,0,0,0,0,0};
      if (d < 24 && k0 < 144) {
        const float4* src = reinterpret_cast<const float4*>(
            Wqkv + ((c >> 5) * 144 + h * 24 + d) * 144 + k0);
        float4 a = src[0], b = src[1];
        o[0]=f2b(a.x); o[1]=f2b(a.y); o[2]=f2b(a.z); o[3]=f2b(a.w);
        o[4]=f2b(b.x); o[5]=f2b(b.y); o[6]=f2b(b.z); o[7]=f2b(b.w);
      }
      *reinterpret_cast<s16x8*>(&WB[c * 168 + k0]) = o;
    }
    __syncthreads();                                   // (b) WB ready
    // ---- qkv GEMM: [128]x[96] over K=144(pad160); wave = 2 row-tiles x 3 col-tiles
    {
      f32x4 acc[2][3];
      #pragma unroll
      for (int i = 0; i < 2; ++i)
        #pragma unroll
        for (int jt = 0; jt < 3; ++jt) acc[i][jt] = z4;
      #pragma unroll
      for (int ks = 0; ks < 5; ++ks) {
        int kk = ks * 32 + (lg << 3);
        s16x8 a0 = *reinterpret_cast<const s16x8*>(&XS[(rg*32 +      ll) * 168 + kk]);
        s16x8 a1 = *reinterpret_cast<const s16x8*>(&XS[(rg*32 + 16 + ll) * 168 + kk]);
        #pragma unroll
        for (int jt = 0; jt < 3; ++jt) {
          s16x8 bb = *reinterpret_cast<const s16x8*>(&WB[((cg*3+jt)*16 + ll) * 168 + kk]);
          acc[0][jt] = __builtin_amdgcn_mfma_f32_16x16x32_bf16(a0, bb, acc[0][jt], 0, 0, 0);
          acc[1][jt] = __builtin_amdgcn_mfma_f32_16x16x32_bf16(a1, bb, acc[1][jt], 0, 0, 0);
        }
      }
      // scatter to QB / KB / VTb (C layout: col=lane&15, row=(lane>>4)*4+r)
      #pragma unroll
      for (int rt = 0; rt < 2; ++rt)
        #pragma unroll
        for (int jt = 0; jt < 3; ++jt) {
          int col = (cg*3 + jt) * 16 + ll;
          #pragma unroll
          for (int r = 0; r < 4; ++r) {
            int n = rg*32 + rt*16 + (lg << 2) + r;
            short bv = f2b(acc[rt][jt][r]);
            if (col < 32)      QB[n*40 + col] = bv;
            else if (col < 64) KB[n*40 + col - 32] = bv;
            else               VTb[(col - 64)*136 + n] = bv;
          }
        }
    }
    __syncthreads();                                   // (c) q/k/vT ready
    // ---- beta + rpb + softmax; wave owns out rows 16w..16w+15
    {
      int qrt = w ^ QXOR;
      s16x8 aq = *reinterpret_cast<const s16x8*>(&QB[(qrt*16 + ll)*40 + (lg << 3)]);
      f32x4 bacc[NT];
      #pragma unroll
      for (int mt = 0; mt < NT; ++mt) {
        s16x8 bk = *reinterpret_cast<const s16x8*>(&KB[(mbase + mt*16 + ll)*40 + (lg << 3)]);
        bacc[mt] = __builtin_amdgcn_mfma_f32_16x16x32_bf16(aq, bk, z4, 0, 0, 0);
      }
      float val[NT][4];
      if constexpr (PATH == 0) {
        #pragma unroll
        for (int r = 0; r < 4; ++r) {
          int n = w*16 + (lg << 2) + r;
          int dn = n >> 6, hn = (n >> 3) & 7, wn = n & 7;
          #pragma unroll
          for (int mt = 0; mt < NT; ++mt) {
            int m = mt*16 + ll;
            int dm = m >> 6, hm = (m >> 3) & 7, wm = m & 7;
            int idx = (dn - dm + 1)*225 + (hn - hm + 7)*15 + (wn - wm + 7);
            val[mt][r] = bacc[mt][r] * SCALE + RPB[idx*6 + h];
          }
        }
      } else {
        #pragma unroll
        for (int mt = 0; mt < NT; ++mt)
          #pragma unroll
          for (int r = 0; r < 4; ++r)
            val[mt][r] = bacc[mt][r] * SCALE;
      }
      float mx[4], si[4];
      #pragma unroll
      for (int r = 0; r < 4; ++r) {
        float m_ = -1e30f;
        #pragma unroll
        for (int mt = 0; mt < NT; ++mt) m_ = fmaxf(m_, val[mt][r]);
        #pragma unroll
        for (int d_ = 1; d_ < 16; d_ <<= 1) m_ = fmaxf(m_, __shfl_xor(m_, d_, 64));
        mx[r] = m_;
      }
      #pragma unroll
      for (int r = 0; r < 4; ++r) {
        float s_ = 0.f;
        #pragma unroll
        for (int mt = 0; mt < NT; ++mt) { float p = __expf(val[mt][r] - mx[r]); val[mt][r] = p; s_ += p; }
        #pragma unroll
        for (int d_ = 1; d_ < 16; d_ <<= 1) s_ += __shfl_xor(s_, d_, 64);
        si[r] = 1.0f / s_;
      }
      short* ALw = AL + w*16*136;
      #pragma unroll
      for (int r = 0; r < 4; ++r) {
        int row = (lg << 2) + r;
        #pragma unroll
        for (int mt = 0; mt < NT; ++mt)
          ALw[row*136 + mt*16 + ll] = f2b(val[mt][r] * si[r]);
      }
    }
    __syncthreads();                                   // (d) all QB/KB reads done
    // ---- stage proj weight strip head h: WB[144][40] (k pad to 32 w/ zeros)
    for (int ch = tid; ch < 144*5; ch += 512) {
      int c = ch / 5, k0 = (ch - c*5) << 3;
      s16x8 o = {0,0,0,0,0,0,0,0};
      if (k0 < 24) {
        const float4* src = reinterpret_cast<const float4*>(
            w_proj + c*288 + COFF + h*24 + k0);
        float4 a = src[0], b = src[1];
        o[0]=f2b(a.x); o[1]=f2b(a.y); o[2]=f2b(a.z); o[3]=f2b(a.w);
        o[4]=f2b(b.x); o[5]=f2b(b.y); o[6]=f2b(b.z); o[7]=f2b(b.w);
      }
      *reinterpret_cast<s16x8*>(&WB[c*40 + k0]) = o;
    }
    // ---- PV: out_h[16][32] = alpha @ V, then store into QB (q is dead)
    {
      f32x4 pacc[2] = {z4, z4};
      #pragma unroll
      for (int ks = 0; ks < NKS; ++ks) {
        s16x8 a = *reinterpret_cast<const s16x8*>(&AL[(w*16 + ll)*136 + ks*32 + (lg << 3)]);
        #pragma unroll
        for (int dt = 0; dt < 2; ++dt) {
          s16x8 bb = *reinterpret_cast<const s16x8*>(&VTb[(dt*16 + ll)*136 + mbase + ks*32 + (lg << 3)]);
          pacc[dt] = __builtin_amdgcn_mfma_f32_16x16x32_bf16(a, bb, pacc[dt], 0, 0, 0);
        }
      }
      #pragma unroll
      for (int dt = 0; dt < 2; ++dt)
        #pragma unroll
        for (int r = 0; r < 4; ++r) {
          int n = w*16 + (lg << 2) + r;
          QB[n*40 + dt*16 + ll] = f2b(pacc[dt][r]);
        }
    }
    __syncthreads();                                   // (e) out_h + Wp ready
    // ---- rank-24 projection update: oacc += out_h @ Wp_h^T
    {
      s16x8 ao = *reinterpret_cast<const s16x8*>(&QB[(w*16 + ll)*40 + (lg << 3)]);
      #pragma unroll
      for (int ct = 0; ct < 9; ++ct) {
        s16x8 bb = *reinterpret_cast<const s16x8*>(&WB[(ct*16 + ll)*40 + (lg << 3)]);
        oacc[ct] = __builtin_amdgcn_mfma_f32_16x16x32_bf16(ao, bb, oacc[ct], 0, 0, 0);
      }
    }
  }
}

__global__ __launch_bounds__(512, 2)
void wmsa_kernel(const float* __restrict__ x,
                 const float* __restrict__ rpb_table,
                 const float* __restrict__ w_self,
                 const float* __restrict__ w_mut,
                 const float* __restrict__ w_proj,
                 const float* __restrict__ b_proj,
                 float* __restrict__ out)
{
  __shared__ short XS[128*168];
  __shared__ short QB[128*40];
  __shared__ short KB[128*40];
  __shared__ short VTb[32*136];
  __shared__ short AL[8*16*136];
  __shared__ short WB[96*168];
  __shared__ float RPB[675*6];

  const int tid = threadIdx.x;
  const int w   = tid >> 6;
  const int l   = tid & 63;
  const int lg  = l >> 4;
  const int ll  = l & 15;
  const int blk = blockIdx.x;

  f32x4 oacc[9];
  const f32x4 z4 = {0.f,0.f,0.f,0.f};
  #pragma unroll
  for (int i = 0; i < 9; ++i) oacc[i] = z4;

  for (int i = tid; i < 675*6; i += 512) RPB[i] = rpb_table[i];

  const float* xg  = x + (size_t)blk * (128*144);
  const float4* xg4 = reinterpret_cast<const float4*>(xg);
  for (int i = tid; i < 128*36; i += 512) {
    int n = i / 36, c4 = (i - n*36) << 2;
    float4 v = xg4[i];
    s16x4 s; s[0]=f2b(v.x); s[1]=f2b(v.y); s[2]=f2b(v.z); s[3]=f2b(v.w);
    *reinterpret_cast<s16x4*>(&XS[n*168 + c4]) = s;
  }
  for (int i = tid; i < 128*6; i += 512) {
    int n = i / 6, c4 = 144 + ((i - n*6) << 2);
    s16x4 zz = {0,0,0,0};
    *reinterpret_cast<s16x4*>(&XS[n*168 + c4]) = zz;
  }
  // (a) barrier inside run_path covers visibility of XS/RPB before first use

  run_path<0>(XS, QB, KB, VTb, AL, WB, RPB, w_self, w_proj, oacc, tid, w, lg, ll);

  __syncthreads();
  // XS <- x + pos for the mutual path
  for (int i = tid; i < 128*144; i += 512) {
    int n = i / 144, c = i - n*144;
    float v = b2f(XS[n*168 + c]) + pos_val(n, c);
    XS[n*168 + c] = f2b(v);
  }
  // next XS read is after two barriers inside run_path<1>

  run_path<1>(XS, QB, KB, VTb, AL, WB, RPB, w_mut, w_proj, oacc, tid, w, lg, ll);

  float* og = out + (size_t)blk * (128*144);
  #pragma unroll
  for (int ct = 0; ct < 9; ++ct) {
    int c = ct*16 + ll;
    float bb = b_proj[c];
    #pragma unroll
    for (int r = 0; r < 4; ++r) {
      int n = w*16 + (lg << 2) + r;
      og[n*144 + c] = oacc[ct][r] + bb;
    }
  }
}

extern "C" void kernel_launch(void* const* d_in, const int* in_sizes, int n_in,
                              void* d_out, int out_size, void* d_ws, size_t ws_size,
                              hipStream_t stream) {
  (void)in_sizes; (void)n_in; (void)out_size; (void)d_ws; (void)ws_size;
  const float* x   = (const float*)d_in[0];
  const float* rpb = (const float*)d_in[1];
  const float* wqs = (const float*)d_in[2];
  const float* wqm = (const float*)d_in[3];
  const float* wp  = (const float*)d_in[4];
  const float* bp  = (const float*)d_in[5];
  wmsa_kernel<<<dim3(1024), dim3(512), 0, stream>>>(x, rpb, wqs, wqm, wp, bp, (float*)d_out);
}

// Round 2
// 183.644 us; speedup vs baseline: 2.0372x; 2.0372x over previous
//
#include <hip/hip_runtime.h>

typedef float  f32x4 __attribute__((ext_vector_type(4)));
typedef short  s16x8 __attribute__((ext_vector_type(8)));
typedef short  s16x4 __attribute__((ext_vector_type(4)));

#define DEVI static __device__ __forceinline__

DEVI short f2b(float f) {
  unsigned u = __builtin_bit_cast(unsigned, f);
  unsigned r = (u + 0x7FFFu + ((u >> 16) & 1u)) >> 16;   // RNE fp32->bf16
  return (short)(unsigned short)r;
}
DEVI float b2f(short s) {
  unsigned u = ((unsigned)(unsigned short)s) << 16;
  return __builtin_bit_cast(float, u);
}

// sine positional encoding, matches _sine_pos_encoding((8,8), 72) tiled x2 over n
DEVI float pos_val(int n, int c) {
  int i = (n & 63) >> 3, j = n & 7;
  float base; int cc;
  if (c < 72) { base = (float)(i + 1); cc = c; }
  else        { base = (float)(j + 1); cc = c - 72; }
  int m = cc >> 1;
  const float SC  = (float)(6.283185307179586 / 8.000001);   // 2*pi/(8+1e-6)
  const float LNT = (float)(9.210340371976184 / 36.0);       // ln(10000)/36
  float arg = base * SC * __expf(-(float)m * LNT);
  return (cc & 1) ? cosf(arg) : sinf(arg);
}

// ---------------- prologue: fragment-ordered weight/bias/pos precompute ----
// WF  : [path][h][combo c=strip*2+ct][ks]  tiles of [64 lanes][8 bf16]
//       lane l elem j = W[strip*144+h*24 + ct*16+(l&15)][ks*32+(l>>4)*8+j], 0-padded
// PF  : [path][h][ct 0..8] tiles; lane l elem j = Wp[ct*16+(l&15)][COFF+h*24+(l>>4)*8+j]
// RPF : [h][w][mt] tiles of [64][4] f32; r -> rpb(n=w*16+(l&15), m=mt*16+4*(l>>4)+r)
// POSB: [128][144] bf16
__global__ void prep_kernel(const float* __restrict__ w_self,
                            const float* __restrict__ w_mut,
                            const float* __restrict__ w_proj,
                            const float* __restrict__ rpb_table,
                            short* WF, short* PF, float* RPF, short* POSB)
{
  int b = blockIdx.x, l = threadIdx.x;
  if (b < 360) {
    int p = b / 180, r1 = b % 180, h = r1 / 30, r2 = r1 % 30, c = r2 / 5, ks = r2 % 5;
    const float* W = p ? w_mut : w_self;
    int strip = c >> 1, ct = c & 1;
    int d = ct * 16 + (l & 15);
    short* dst = WF + b * 512 + l * 8;
    #pragma unroll
    for (int j = 0; j < 8; ++j) {
      int k = ks * 32 + (l >> 4) * 8 + j;
      float v = (d < 24 && k < 144) ? W[(strip * 144 + h * 24 + d) * 144 + k] : 0.f;
      dst[j] = f2b(v);
    }
  } else if (b < 468) {
    int b2 = b - 360, ct = b2 % 9, h = (b2 / 9) % 6, p = b2 / 54;
    int cf = ct * 16 + (l & 15);
    short* dst = PF + b2 * 512 + l * 8;
    #pragma unroll
    for (int j = 0; j < 8; ++j) {
      int d = (l >> 4) * 8 + j;
      float v = (d < 24) ? w_proj[cf * 288 + (p ? 0 : 144) + h * 24 + d] : 0.f;
      dst[j] = f2b(v);
    }
  } else if (b < 852) {
    int b3 = b - 468, mt = b3 % 8, w = (b3 / 8) % 8, h = b3 / 64;
    int n = w * 16 + (l & 15);
    int dn = n >> 6, hn = (n >> 3) & 7, wn = n & 7;
    f32x4 o;
    #pragma unroll
    for (int r = 0; r < 4; ++r) {
      int m = mt * 16 + ((l >> 4) << 2) + r;
      int dm = m >> 6, hm = (m >> 3) & 7, wm = m & 7;
      int idx = (dn - dm + 1) * 225 + (hn - hm + 7) * 15 + (wn - wm + 7);
      o[r] = rpb_table[idx * 6 + h];
    }
    *reinterpret_cast<f32x4*>(RPF + b3 * 256 + l * 4) = o;
  } else {
    int e = (b - 852) * 64 + l;           // 0..18431
    int n = e / 144, c = e - n * 144;
    POSB[e] = f2b(pos_val(n, c));
  }
}

// ---------------- main fused kernel ----------------
// LDS: XS[128][168] bf16 (K-pad 160); QB[128][40] (q / alpha-stage / out_h);
//      KB[128][40]; VTb[32][136] (v^T, rows 24..31 zero); PFB[9*512] proj frags.
// Total 81408 B -> 2 blocks/CU.
template<int PATH>
DEVI void run_path(short* XS, short* QB, short* KB, short* VTb, short* PFB,
                   const short* WF, const short* PF, const float* RPF,
                   f32x4 (&oacc)[9], int tid, int w, int lg, int ll, int l64)
{
  constexpr int NT  = PATH ? 4 : 8;          // beta m-tiles per wave
  constexpr int NKS = PATH ? 2 : 4;          // PV k-steps (32 m each)
  const float SCALE = 0.20412414523193154f;  // 24^-0.5
  const int mbase = PATH ? (w >> 2) * 64 : 0;
  const int qrow0 = (PATH ? (w ^ 4) : w) * 16;
  const f32x4 z4 = {0.f, 0.f, 0.f, 0.f};

  for (int h = 0; h < 6; ++h) {
    const short* WFh = WF + (PATH * 6 + h) * 30 * 512;
    const short* PFh = PF + (PATH * 6 + h) * 9 * 512;
    __syncthreads();                                   // A: prev-head reads done
    // stage proj frags (9216 B) — consumed after barrier B
    for (int i = tid; i < 576; i += 512)
      reinterpret_cast<s16x8*>(PFB)[i] = reinterpret_cast<const s16x8*>(PFh)[i];
    // ---- qkv GEMM: 48 16x16 tiles, wave owns t in [6w, 6w+6), t = c*8 + nt
    {
      int t0 = 6 * w, t1 = t0 + 6;
      for (int c = t0 >> 3; c * 8 < t1; ++c) {
        s16x8 wa[5];
        const s16x8* wp = reinterpret_cast<const s16x8*>(WFh + c * 5 * 512 + l64 * 8);
        #pragma unroll
        for (int ks = 0; ks < 5; ++ks) wa[ks] = wp[ks * 64];
        int lo = (c * 8 > t0) ? c * 8 : t0;
        int hi = (c * 8 + 8 < t1) ? c * 8 + 8 : t1;
        for (int t = lo; t < hi; ++t) {
          int nt = t & 7;
          f32x4 acc = z4;
          #pragma unroll
          for (int ks = 0; ks < 5; ++ks) {
            s16x8 xf = *reinterpret_cast<const s16x8*>(&XS[(nt * 16 + ll) * 168 + ks * 32 + lg * 8]);
            if (c < 4) acc = __builtin_amdgcn_mfma_f32_16x16x32_bf16(wa[ks], xf, acc, 0, 0, 0);
            else       acc = __builtin_amdgcn_mfma_f32_16x16x32_bf16(xf, wa[ks], acc, 0, 0, 0);
          }
          s16x4 o;
          #pragma unroll
          for (int r = 0; r < 4; ++r) o[r] = f2b(acc[r]);
          int ct = c & 1;
          if (c < 2)       // q^T tile: C[cfeat][n] -> QB[n][cfeat], 4 consec cfeat
            *reinterpret_cast<s16x4*>(&QB[(nt * 16 + ll) * 40 + ct * 16 + lg * 4]) = o;
          else if (c < 4)
            *reinterpret_cast<s16x4*>(&KB[(nt * 16 + ll) * 40 + ct * 16 + lg * 4]) = o;
          else             // v tile: C[n][d] -> VTb[d][n], 4 consec n
            *reinterpret_cast<s16x4*>(&VTb[(ct * 16 + ll) * 136 + nt * 16 + lg * 4]) = o;
        }
      }
    }
    __syncthreads();                                   // B: q/k/vT/PFB ready
    // ---- beta^T = mfma(K, q): C[m][n], lane: n = qrow-local l&15, m = 4lg+r (+16mt)
    f32x4 bacc[NT];
    {
      s16x8 qf = *reinterpret_cast<const s16x8*>(&QB[(qrow0 + ll) * 40 + lg * 8]);
      #pragma unroll
      for (int mt = 0; mt < NT; ++mt) {
        s16x8 kf = *reinterpret_cast<const s16x8*>(&KB[(mbase + mt * 16 + ll) * 40 + lg * 8]);
        bacc[mt] = __builtin_amdgcn_mfma_f32_16x16x32_bf16(kf, qf, z4, 0, 0, 0);
      }
    }
    if (PATH) __syncthreads();                         // C: all cross-wave q reads done
    // ---- softmax over m (no max-sub: |beta*SCALE+rpb| <~ 7)
    float vsum = 0.f;
    #pragma unroll
    for (int mt = 0; mt < NT; ++mt) {
      if (PATH == 0) {
        f32x4 rp = *reinterpret_cast<const f32x4*>(RPF + (((h * 8 + w) * 8) + mt) * 256 + l64 * 4);
        #pragma unroll
        for (int r = 0; r < 4; ++r) {
          float p = __expf(fmaf(bacc[mt][r], SCALE, rp[r]));
          bacc[mt][r] = p; vsum += p;
        }
      } else {
        #pragma unroll
        for (int r = 0; r < 4; ++r) {
          float p = __expf(bacc[mt][r] * SCALE);
          bacc[mt][r] = p; vsum += p;
        }
      }
    }
    vsum += __shfl_xor(vsum, 16, 64);
    vsum += __shfl_xor(vsum, 32, 64);
    float inv = 1.0f / vsum;
    // ---- PV^T = mfma(V^T, alpha^T): stage alpha 32-m slab in dead q rows (wave-private)
    short* TP = QB + (w * 16) * 40;
    f32x4 pacc[2] = {z4, z4};
    #pragma unroll
    for (int ks = 0; ks < NKS; ++ks) {
      #pragma unroll
      for (int b2 = 0; b2 < 2; ++b2) {
        int mt = 2 * ks + b2;
        s16x4 o;
        #pragma unroll
        for (int r = 0; r < 4; ++r) o[r] = f2b(bacc[mt][r] * inv);
        *reinterpret_cast<s16x4*>(&TP[ll * 40 + b2 * 16 + lg * 4]) = o;
      }
      s16x8 af = *reinterpret_cast<const s16x8*>(&TP[ll * 40 + lg * 8]);
      #pragma unroll
      for (int dt = 0; dt < 2; ++dt) {
        s16x8 vf = *reinterpret_cast<const s16x8*>(&VTb[(dt * 16 + ll) * 136 + mbase + ks * 32 + lg * 8]);
        pacc[dt] = __builtin_amdgcn_mfma_f32_16x16x32_bf16(vf, af, pacc[dt], 0, 0, 0);
      }
    }
    // out_h^T C[d][n] -> TP[n-local][d], b64 stores (wave-private rows)
    #pragma unroll
    for (int dt = 0; dt < 2; ++dt) {
      s16x4 o;
      #pragma unroll
      for (int r = 0; r < 4; ++r) o[r] = f2b(pacc[dt][r]);
      *reinterpret_cast<s16x4*>(&TP[ll * 40 + dt * 16 + lg * 4]) = o;
    }
    // ---- rank-24 projection update: oacc[n][c] += out_h @ Wp_h^T
    {
      s16x8 of = *reinterpret_cast<const s16x8*>(&TP[ll * 40 + lg * 8]);
      #pragma unroll
      for (int ct = 0; ct < 9; ++ct) {
        s16x8 pf = *reinterpret_cast<const s16x8*>(&PFB[ct * 512 + l64 * 8]);
        oacc[ct] = __builtin_amdgcn_mfma_f32_16x16x32_bf16(of, pf, oacc[ct], 0, 0, 0);
      }
    }
  }
}

__global__ __launch_bounds__(512, 4)
void wmsa_kernel(const float* __restrict__ x,
                 const short* __restrict__ WF,
                 const short* __restrict__ PF,
                 const float* __restrict__ RPF,
                 const short* __restrict__ POSB,
                 const float* __restrict__ b_proj,
                 float* __restrict__ out)
{
  __shared__ short XS[128 * 168];
  __shared__ short QB[128 * 40];
  __shared__ short KB[128 * 40];
  __shared__ short VTb[32 * 136];
  __shared__ short PFB[9 * 512];

  const int tid = threadIdx.x;
  const int w   = tid >> 6;
  const int l64 = tid & 63;
  const int lg  = l64 >> 4;
  const int ll  = l64 & 15;
  const int blk = blockIdx.x;

  f32x4 oacc[9];
  const f32x4 z4 = {0.f, 0.f, 0.f, 0.f};
  #pragma unroll
  for (int i = 0; i < 9; ++i) oacc[i] = z4;

  // stage x -> XS bf16 (cols 144..167 zero)
  const float* xg = x + (size_t)blk * (128 * 144);
  for (int i = tid; i < 128 * 18; i += 512) {
    int n = i / 18, c8 = (i - n * 18) * 8;
    const float4* src = reinterpret_cast<const float4*>(xg + n * 144 + c8);
    float4 a = src[0], b = src[1];
    s16x8 o;
    o[0]=f2b(a.x); o[1]=f2b(a.y); o[2]=f2b(a.z); o[3]=f2b(a.w);
    o[4]=f2b(b.x); o[5]=f2b(b.y); o[6]=f2b(b.z); o[7]=f2b(b.w);
    *reinterpret_cast<s16x8*>(&XS[n * 168 + c8]) = o;
  }
  for (int i = tid; i < 128 * 3; i += 512) {
    int n = i / 3, c8 = 144 + (i - n * 3) * 8;
    s16x8 zz = {0,0,0,0,0,0,0,0};
    *reinterpret_cast<s16x8*>(&XS[n * 168 + c8]) = zz;
  }
  // barrier A inside run_path covers XS visibility

  run_path<0>(XS, QB, KB, VTb, PFB, WF, PF, RPF, oacc, tid, w, lg, ll, l64);

  // XS <- x + pos  (all XS reads of path 0 completed before barrier B of h=5)
  for (int i = tid; i < 2304; i += 512) {
    int n = i / 18, c8 = (i - n * 18) * 8;
    s16x8 xv = *reinterpret_cast<const s16x8*>(&XS[n * 168 + c8]);
    s16x8 pv = reinterpret_cast<const s16x8*>(POSB)[i];
    s16x8 o;
    #pragma unroll
    for (int j = 0; j < 8; ++j) o[j] = f2b(b2f(xv[j]) + b2f(pv[j]));
    *reinterpret_cast<s16x8*>(&XS[n * 168 + c8]) = o;
  }
  // barrier A of mutual h=0 orders update -> GEMM reads

  run_path<1>(XS, QB, KB, VTb, PFB, WF, PF, RPF, oacc, tid, w, lg, ll, l64);

  float* og = out + (size_t)blk * (128 * 144);
  #pragma unroll
  for (int ct = 0; ct < 9; ++ct) {
    int c = ct * 16 + ll;
    float bb = b_proj[c];
    #pragma unroll
    for (int r = 0; r < 4; ++r) {
      int n = w * 16 + lg * 4 + r;
      og[n * 144 + c] = oacc[ct][r] + bb;
    }
  }
}

extern "C" void kernel_launch(void* const* d_in, const int* in_sizes, int n_in,
                              void* d_out, int out_size, void* d_ws, size_t ws_size,
                              hipStream_t stream) {
  (void)in_sizes; (void)n_in; (void)out_size; (void)ws_size;
  const float* x   = (const float*)d_in[0];
  const float* rpb = (const float*)d_in[1];
  const float* wqs = (const float*)d_in[2];
  const float* wqm = (const float*)d_in[3];
  const float* wp  = (const float*)d_in[4];
  const float* bp  = (const float*)d_in[5];

  short* WF   = (short*)d_ws;                      // 360*512 bf16 = 368640 B
  short* PF   = WF + 360 * 512;                    // 108*512 bf16 = 110592 B
  float* RPF  = (float*)((char*)d_ws + 479232);    // 384*256 f32  = 393216 B
  short* POSB = (short*)((char*)d_ws + 872448);    // 18432 bf16   =  36864 B

  prep_kernel<<<dim3(1140), dim3(64), 0, stream>>>(wqs, wqm, wp, rpb, WF, PF, RPF, POSB);
  wmsa_kernel<<<dim3(1024), dim3(512), 0, stream>>>(x, WF, PF, RPF, POSB, bp, (float*)d_out);
}